// Round 6
// baseline (2162.679 us; speedup 1.0000x reference)
//
#include <hip/hip_runtime.h>

// ---------------- problem constants ----------------
#define BATCH     32
#define T_SAMP    480000
#define NFRAMES   2998
#define KLEN      400
#define NMEL      80
#define EPS_F     1.1920928955078125e-07f
#define SCALE2    1073741824.0f   // 32768^2, re-applied before log (A kept unscaled)

#define ALS 36                    // A slab row stride (floats): 144 B, 16B-aligned rows
#define BLS 132                   // B slab row stride: 528 B, 16B-aligned rows
#define SPS 132                   // Sp row stride

// ---------------- kernel 0: zero the means accumulator ----------------
__global__ __launch_bounds__(256) void FbankWrapper_14285061226526_kernel(float* means)
{
    int i = blockIdx.x * 256 + threadIdx.x;
    if (i < BATCH * NMEL) means[i] = 0.f;
}

// ---------------- kernel 1: fully-fused fp32 reference-grade pipeline ----------
// one block = 32 frames. A (k-major fp32) staged per 64-k slab from wav (L1-hot),
// B staged per slab from dft tables, 32x128 fp32 VALU GEMM per col-pass,
// spectrum+mel+log in fp32. No reduced precision anywhere.
__global__ __launch_bounds__(256) void k_main(const float* __restrict__ wav,
                                              const float* __restrict__ window,
                                              const float* __restrict__ melf,
                                              const float* __restrict__ dcos,
                                              const float* __restrict__ dsin,
                                              float* __restrict__ out)
{
    __shared__ float Al[64][ALS];     //  9,216 B  (k-local x frame)
    __shared__ float Bl[64][BLS];     // 33,792 B  (k-local x col)
    __shared__ float Sp[32][SPS];     // 16,896 B  (frame x col)  -- 59,904 total

    const int tid  = threadIdx.x;
    const int tile = blockIdx.x;      // 0..2997

    // ---- per-thread frame role for A staging: 8 threads per frame ----
    const int fr = tid >> 3;          // frame 0..31
    const int og = tid & 7;
    const int fb = tile * 32 + fr;
    const int pb = fb / NFRAMES;
    const int pf = fb - pb * NFRAMES;
    const float* sig = wav + (size_t)pb * T_SAMP + (size_t)pf * 160;

    // ---- frame mean via 8-lane xor-shuffle (covers k=0..399 exactly once) ----
    float s = 0.f;
    #pragma unroll
    for (int i = 0; i < 7; ++i) {
        int k0 = og * 8 + 64 * i;
        if (k0 < KLEN) {
            float4 x0 = *(const float4*)(sig + k0);
            float4 x1 = *(const float4*)(sig + k0 + 4);
            s += x0.x + x0.y + x0.z + x0.w + x1.x + x1.y + x1.z + x1.w;
        }
    }
    s += __shfl_xor(s, 1);
    s += __shfl_xor(s, 2);
    s += __shfl_xor(s, 4);
    const float fmean = s * (1.0f / (float)KLEN);

    // ---- GEMM / staging / mel thread roles ----
    const int mi = (tid & 7) * 4;     // GEMM: 4 consecutive frame rows
    const int ni = (tid >> 3) * 4;    // GEMM: 4 consecutive cols (of 128)
    const int bc = tid & 127;         // B staging: col-local
    const int bk = (tid >> 7) * 32;   // B staging: k-local base (0 or 32)
    const int mf = tid & 31;          // mel: frame
    const int mg = tid >> 5;          // mel: 10-mel group (0..7)

    float accm[10];
    #pragma unroll
    for (int t = 0; t < 10; ++t) accm[t] = 0.f;

    for (int n0 = 0; n0 < 512; n0 += 128) {   // 4 column passes
        float C[4][4];
        #pragma unroll
        for (int r = 0; r < 4; ++r)
            #pragma unroll
            for (int c = 0; c < 4; ++c) C[r][c] = 0.f;

        const int cg = n0 + bc;               // global DFT col for staging
        const float* btab = ((cg & 1) ? dsin : dcos) + (size_t)(cg >> 1) * 512;

        for (int kc = 0; kc < 7; ++kc) {      // 7 k-slabs of 64 (448 >= 400, zero-pad)
            __syncthreads();                  // prior slab's LDS reads / mel reads done

            // -- stage A slab: thread writes k-local og*8..og*8+7 for its frame --
            {
                int kg0 = kc * 64 + og * 8;
                float yv[8];
                if (kg0 < KLEN) {
                    float4 x0 = *(const float4*)(sig + kg0);
                    float4 x1 = *(const float4*)(sig + kg0 + 4);
                    float4 w0 = *(const float4*)(window + kg0);
                    float4 w1 = *(const float4*)(window + kg0 + 4);
                    float xm1 = (kg0 > 0) ? sig[kg0 - 1] : x0.x;
                    float xs[8] = {x0.x, x0.y, x0.z, x0.w, x1.x, x1.y, x1.z, x1.w};
                    float ws[8] = {w0.x, w0.y, w0.z, w0.w, w1.x, w1.y, w1.z, w1.w};
                    #pragma unroll
                    for (int j = 0; j < 8; ++j) {
                        float xp = (j == 0) ? xm1 : xs[j - 1];
                        // (x-m) - 0.97*(xp-m) = x - 0.97*xp - 0.03*m  (unscaled)
                        yv[j] = (xs[j] - 0.97f * xp - 0.03f * fmean) * ws[j];
                    }
                } else {
                    #pragma unroll
                    for (int j = 0; j < 8; ++j) yv[j] = 0.f;
                }
                int kl = og * 8;
                #pragma unroll
                for (int j = 0; j < 8; ++j) Al[kl + j][fr] = yv[j];
            }
            // -- stage B slab: thread covers col bc, k-local bk..bk+31 --
            {
                #pragma unroll 8
                for (int j = 0; j < 32; ++j) {
                    int kg = kc * 64 + bk + j;
                    Bl[bk + j][bc] = (kg < KLEN) ? btab[kg] : 0.f;
                }
            }
            __syncthreads();                  // slab staged

            // -- 32x128 fp32 GEMM, 4x4 register tile per thread --
            #pragma unroll 4
            for (int k = 0; k < 64; ++k) {
                float4 a = *(const float4*)&Al[k][mi];
                float4 b = *(const float4*)&Bl[k][ni];
                C[0][0] += a.x * b.x; C[0][1] += a.x * b.y;
                C[0][2] += a.x * b.z; C[0][3] += a.x * b.w;
                C[1][0] += a.y * b.x; C[1][1] += a.y * b.y;
                C[1][2] += a.y * b.z; C[1][3] += a.y * b.w;
                C[2][0] += a.z * b.x; C[2][1] += a.z * b.y;
                C[2][2] += a.z * b.z; C[2][3] += a.z * b.w;
                C[3][0] += a.w * b.x; C[3][1] += a.w * b.y;
                C[3][2] += a.w * b.z; C[3][3] += a.w * b.w;
            }
        }

        // ---- stage C into Sp[frame][col] ----
        __syncthreads();                      // last slab's Al/Bl reads done
        #pragma unroll
        for (int r = 0; r < 4; ++r)
            #pragma unroll
            for (int c = 0; c < 4; ++c)
                Sp[mi + r][ni + c] = C[r][c];
        __syncthreads();                      // Sp visible

        // ---- spectrum + mel over this pass's 64 bins (cols 2b=re, 2b+1=im) ----
        int kb0 = n0 >> 1;
        for (int jb = 0; jb < 64; ++jb) {
            float2 v = *(const float2*)&Sp[mf][2 * jb];
            float sv = v.x * v.x + v.y * v.y;
            const float* wr = melf + (size_t)(kb0 + jb) * NMEL + mg * 10;
            #pragma unroll
            for (int t = 0; t < 5; ++t) {
                float2 w = *(const float2*)(wr + 2 * t);
                accm[2 * t]     += sv * w.x;
                accm[2 * t + 1] += sv * w.y;
            }
        }
        // next pass's first barrier orders these Sp reads vs the next Al/Bl writes
    }

    // ---- re-apply 32768^2, log, fp32 store ----
    {
        size_t row = (size_t)tile * 32 + mf;
        #pragma unroll
        for (int t = 0; t < 10; ++t)
            out[row * NMEL + mg * 10 + t] = logf(fmaxf(accm[t] * SCALE2, EPS_F));
    }
}

// ---------------- kernel 2: per-(batch,mel) sums over frames (fp32) ----------
__global__ __launch_bounds__(256) void k_mean(const float* __restrict__ out,
                                              float* __restrict__ means)
{
    __shared__ float red[240];
    int b = blockIdx.y, tid = threadIdx.x;
    int f0   = blockIdx.x * 375;
    int fend = min(f0 + 375, NFRAMES);
    int r = tid / 80, m = tid - r * 80;
    if (tid < 240) {
        float s = 0.f;
        const float* base = out + (size_t)b * NFRAMES * NMEL;
        for (int f = f0 + r; f < fend; f += 3)
            s += base[(size_t)f * NMEL + m];
        red[tid] = s;
    }
    __syncthreads();
    if (tid < 80)
        atomicAdd(&means[b * NMEL + tid], red[tid] + red[tid + 80] + red[tid + 160]);
}

// ---------------- kernel 3: subtract mean in-place (fp32) ----------
__global__ __launch_bounds__(256) void k_norm(const float* __restrict__ means,
                                              float* __restrict__ out)
{
    const int PER = NFRAMES * NMEL;           // 239,840
    int b = blockIdx.y;
    int e = blockIdx.x * 256 + threadIdx.x;
    if (e < PER) {
        int m = e % NMEL;
        size_t idx = (size_t)b * PER + e;
        out[idx] = out[idx] - means[b * NMEL + m] * (1.0f / (float)NFRAMES);
    }
}

// ---------------- launch ----------------
extern "C" void kernel_launch(void* const* d_in, const int* in_sizes, int n_in,
                              void* d_out, int out_size, void* d_ws, size_t ws_size,
                              hipStream_t stream)
{
    const float* wav    = (const float*)d_in[0];
    const float* window = (const float*)d_in[1];
    const float* melf   = (const float*)d_in[2];
    const float* dcos   = (const float*)d_in[3];
    const float* dsin   = (const float*)d_in[4];
    float* out   = (float*)d_out;
    float* means = (float*)d_ws;              // 10,240 B only

    FbankWrapper_14285061226526_kernel<<<10, 256, 0, stream>>>(means);
    k_main<<<2998, 256, 0, stream>>>(wav, window, melf, dcos, dsin, out);
    k_mean<<<dim3(8, BATCH), 256, 0, stream>>>(out, means);
    k_norm<<<dim3((NFRAMES * NMEL + 255) / 256, BATCH), 256, 0, stream>>>(means, out);
}

// Round 7
// 514.784 us; speedup vs baseline: 4.2011x; 4.2011x over previous
//
#include <hip/hip_runtime.h>

// ---------------- problem constants ----------------
#define BATCH     32
#define T_SAMP    480000
#define NFRAMES   2998
#define KLEN      400
#define KA        416             // 13*32 ; k 400..415 zero-padded
#define NMEL      80
#define EPS_F     1.1920928955078125e-07f
#define SCALE2    1073741824.0f   // 32768^2, re-applied before log (A unscaled)
#define SPLIT_S   2048.0f         // lo-plane scale (keeps lo in fp16 normal range)
#define SPLIT_INV 4.8828125e-4f   // 1/2048
#define MTS       260             // melfT row stride (floats)

typedef _Float16 f16x8 __attribute__((ext_vector_type(8)));
typedef float    f32x4 __attribute__((ext_vector_type(4)));

// ---------------- kernel 0: zero the means accumulator ----------------
__global__ __launch_bounds__(256) void FbankWrapper_14285061226526_kernel(float* means)
{
    int i = blockIdx.x * 256 + threadIdx.x;
    if (i < BATCH * NMEL) means[i] = 0.f;
}

// ---------------- kernel 1: mel filter transpose + per-mel bin ranges ----------
__global__ __launch_bounds__(256) void k_setup(const float* __restrict__ melf,
                                               int* __restrict__ mlo,
                                               int* __restrict__ mhi,
                                               float* __restrict__ melfT)
{
    int m = threadIdx.x;
    if (m < NMEL) {
        int lo = 256, hi = 0;
        for (int k = 0; k < 257; ++k) {
            float w = melf[(size_t)k * NMEL + m];
            melfT[(size_t)m * MTS + k] = w;
            if (w > 0.f) { if (k < lo) lo = k; hi = k + 1; }
        }
        mlo[m] = lo;
        mhi[m] = hi;
    }
}

// ---------------- kernel 2: fused prep + split-fp16 MFMA DFT + spectrum + mel ----
// one block = 32 frames. A = Ah + Al/2048 (fp16 planes, LDS-resident, full K).
// B read from dcos/dsin global (L2-hot) and split in registers per k-step.
// C = Ah*Bh + (Ah*Bl + Al*Bh)/2048  (3 accumulator sets, fp32).
// K-loop is barrier-free; barriers only around the per-pass Sp round-trip.
__global__ __launch_bounds__(256) void k_main(const float* __restrict__ wav,
                                              const float* __restrict__ window,
                                              const float* __restrict__ melfT,
                                              const int* __restrict__ mlo,
                                              const int* __restrict__ mhi,
                                              const float* __restrict__ dcos,
                                              const float* __restrict__ dsin,
                                              float* __restrict__ out)
{
    __shared__ __align__(16) _Float16 Ah[32][424];   // 27,136 B
    __shared__ __align__(16) _Float16 Al[32][424];   // 27,136 B
    __shared__ __align__(16) float    Sp[32][66];    //  8,448 B  (62,720 total)

    const int tid  = threadIdx.x;
    const int lane = tid & 63;
    const int wid  = tid >> 6;
    const int tile = blockIdx.x;            // 0..2997

    // ---- prep: 8 threads per frame; mean via 8-lane shuffle; split to hi/lo ----
    {
        int fr = tid >> 3, og = tid & 7;
        int fb = tile * 32 + fr;
        int b  = fb / NFRAMES;
        int f  = fb - b * NFRAMES;
        const float* sig = wav + (size_t)b * T_SAMP + (size_t)f * 160;

        float s = 0.f;
        #pragma unroll
        for (int i = 0; i < 7; ++i) {
            int k0 = og * 8 + 64 * i;
            if (k0 < KLEN) {
                float4 x0 = *(const float4*)(sig + k0);
                float4 x1 = *(const float4*)(sig + k0 + 4);
                s += x0.x + x0.y + x0.z + x0.w + x1.x + x1.y + x1.z + x1.w;
            }
        }
        s += __shfl_xor(s, 1);
        s += __shfl_xor(s, 2);
        s += __shfl_xor(s, 4);
        float mean = s * (1.0f / (float)KLEN);

        #pragma unroll
        for (int i = 0; i < 7; ++i) {
            int k0 = og * 8 + 64 * i;
            if (k0 < KA) {
                f16x8 hv, lv;
                if (k0 < KLEN) {
                    float4 x0 = *(const float4*)(sig + k0);
                    float4 x1 = *(const float4*)(sig + k0 + 4);
                    float4 w0 = *(const float4*)(window + k0);
                    float4 w1 = *(const float4*)(window + k0 + 4);
                    float xm1 = (k0 > 0) ? sig[k0 - 1] : x0.x;
                    float xs[8] = {x0.x, x0.y, x0.z, x0.w, x1.x, x1.y, x1.z, x1.w};
                    float wv[8] = {w0.x, w0.y, w0.z, w0.w, w1.x, w1.y, w1.z, w1.w};
                    #pragma unroll
                    for (int j = 0; j < 8; ++j) {
                        float xp = (j == 0) ? xm1 : xs[j - 1];
                        float y  = (xs[j] - 0.97f * xp - 0.03f * mean) * wv[j];
                        _Float16 h = (_Float16)y;
                        hv[j] = h;
                        lv[j] = (_Float16)((y - (float)h) * SPLIT_S);
                    }
                } else {
                    #pragma unroll
                    for (int j = 0; j < 8; ++j) { hv[j] = (_Float16)0.f; lv[j] = (_Float16)0.f; }
                }
                *(f16x8*)&Ah[fr][k0] = hv;
                *(f16x8*)&Al[fr][k0] = lv;
            }
        }
    }
    __syncthreads();                        // A planes ready

    const int wn = wid;                     // wave -> 32-col strip
    const int q  = lane >> 4, lr = lane & 15;
    const int mf = tid & 31;                // mel: frame
    const int mg = tid >> 5;                // mel: 0..7 (mels mg, mg+8, ..., mg+72)

    int lo10[10], hi10[10];
    #pragma unroll
    for (int t = 0; t < 10; ++t) { lo10[t] = mlo[mg + 8 * t]; hi10[t] = mhi[mg + 8 * t]; }

    float accm[10];
    #pragma unroll
    for (int t = 0; t < 10; ++t) accm[t] = 0.f;

    for (int n0 = 0; n0 < 512; n0 += 128) {
        f32x4 aM[2][2], aX[2][2], aY[2][2];
        #pragma unroll
        for (int mt = 0; mt < 2; ++mt)
            #pragma unroll
            for (int nt = 0; nt < 2; ++nt) {
                aM[mt][nt] = (f32x4){0.f, 0.f, 0.f, 0.f};
                aX[mt][nt] = (f32x4){0.f, 0.f, 0.f, 0.f};
                aY[mt][nt] = (f32x4){0.f, 0.f, 0.f, 0.f};
            }

        // per-lane B row pointers (col n, k-chunk q)
        const float* bp[2];
        #pragma unroll
        for (int nt = 0; nt < 2; ++nt) {
            int n = n0 + wn * 32 + nt * 16 + lr;
            bp[nt] = ((n & 1) ? dsin : dcos) + (size_t)(n >> 1) * 512 + q * 8;
        }

        // ---- barrier-free K loop: LDS A-frags, global B + register split ----
        for (int kk = 0; kk < KA; kk += 32) {
            f16x8 ah[2], al[2], bh[2], bl[2];
            #pragma unroll
            for (int mt = 0; mt < 2; ++mt) {
                ah[mt] = *(const f16x8*)&Ah[mt * 16 + lr][kk + q * 8];
                al[mt] = *(const f16x8*)&Al[mt * 16 + lr][kk + q * 8];
            }
            #pragma unroll
            for (int nt = 0; nt < 2; ++nt) {
                float4 b0 = *(const float4*)(bp[nt] + kk);
                float4 b1 = *(const float4*)(bp[nt] + kk + 4);
                float bv[8] = {b0.x, b0.y, b0.z, b0.w, b1.x, b1.y, b1.z, b1.w};
                #pragma unroll
                for (int j = 0; j < 8; ++j) {
                    _Float16 h = (_Float16)bv[j];
                    bh[nt][j] = h;
                    bl[nt][j] = (_Float16)((bv[j] - (float)h) * SPLIT_S);
                }
            }
            #pragma unroll
            for (int mt = 0; mt < 2; ++mt)
                #pragma unroll
                for (int nt = 0; nt < 2; ++nt) {
                    aM[mt][nt] = __builtin_amdgcn_mfma_f32_16x16x32_f16(
                        ah[mt], bh[nt], aM[mt][nt], 0, 0, 0);
                    aX[mt][nt] = __builtin_amdgcn_mfma_f32_16x16x32_f16(
                        ah[mt], bl[nt], aX[mt][nt], 0, 0, 0);
                    aY[mt][nt] = __builtin_amdgcn_mfma_f32_16x16x32_f16(
                        al[mt], bh[nt], aY[mt][nt], 0, 0, 0);
                }
        }

        // ---- spectrum epilogue: combine splits, pair re/im via shfl ----
        __syncthreads();                    // prior pass's mel Sp-reads done
        #pragma unroll
        for (int mt = 0; mt < 2; ++mt)
            #pragma unroll
            for (int nt = 0; nt < 2; ++nt)
                #pragma unroll
                for (int r = 0; r < 4; ++r) {
                    float v = aM[mt][nt][r]
                            + (aX[mt][nt][r] + aY[mt][nt][r]) * SPLIT_INV;
                    float o = __shfl_xor(v, 1);
                    if ((lane & 1) == 0) {
                        int row = mt * 16 + q * 4 + r;               // frame 0..31
                        int bin = (wn * 32 + nt * 16 + lr) >> 1;     // 0..63
                        Sp[row][bin] = v * v + o * o;
                    }
                }
        __syncthreads();                    // Sp visible

        // ---- sparse mel: per-mel contiguous bin ranges ∩ this pass ----
        int kb0 = n0 >> 1;
        #pragma unroll
        for (int t = 0; t < 10; ++t) {
            int ks = lo10[t] > kb0 ? lo10[t] : kb0;
            int ke = hi10[t] < kb0 + 64 ? hi10[t] : kb0 + 64;
            const float* wrow = melfT + (size_t)(mg + 8 * t) * MTS;
            for (int k = ks; k < ke; ++k)
                accm[t] += Sp[mf][k - kb0] * wrow[k];
        }
    }

    // ---- re-apply 32768^2, log, fp32 store ----
    {
        size_t row = (size_t)tile * 32 + mf;
        #pragma unroll
        for (int t = 0; t < 10; ++t)
            out[row * NMEL + mg + 8 * t] = logf(fmaxf(accm[t] * SCALE2, EPS_F));
    }
}

// ---------------- kernel 3: per-(batch,mel) sums over frames (fp32) ----------
__global__ __launch_bounds__(256) void k_mean(const float* __restrict__ out,
                                              float* __restrict__ means)
{
    __shared__ float red[240];
    int b = blockIdx.y, tid = threadIdx.x;
    int f0   = blockIdx.x * 375;
    int fend = min(f0 + 375, NFRAMES);
    int r = tid / 80, m = tid - r * 80;
    if (tid < 240) {
        float s = 0.f;
        const float* base = out + (size_t)b * NFRAMES * NMEL;
        for (int f = f0 + r; f < fend; f += 3)
            s += base[(size_t)f * NMEL + m];
        red[tid] = s;
    }
    __syncthreads();
    if (tid < 80)
        atomicAdd(&means[b * NMEL + tid], red[tid] + red[tid + 80] + red[tid + 160]);
}

// ---------------- kernel 4: subtract mean in-place (fp32) ----------
__global__ __launch_bounds__(256) void k_norm(const float* __restrict__ means,
                                              float* __restrict__ out)
{
    const int PER = NFRAMES * NMEL;           // 239,840
    int b = blockIdx.y;
    int e = blockIdx.x * 256 + threadIdx.x;
    if (e < PER) {
        int m = e % NMEL;
        size_t idx = (size_t)b * PER + e;
        out[idx] = out[idx] - means[b * NMEL + m] * (1.0f / (float)NFRAMES);
    }
}

// ---------------- launch ----------------
extern "C" void kernel_launch(void* const* d_in, const int* in_sizes, int n_in,
                              void* d_out, int out_size, void* d_ws, size_t ws_size,
                              hipStream_t stream)
{
    const float* wav    = (const float*)d_in[0];
    const float* window = (const float*)d_in[1];
    const float* melf   = (const float*)d_in[2];
    const float* dcos   = (const float*)d_in[3];
    const float* dsin   = (const float*)d_in[4];
    float* out = (float*)d_out;

    // ws layout (94,080 B total; round-6 proved >= 436 KB usable):
    //   means fp32 32*80   @ 0        (10,240)
    //   mlo   int  80      @ 10,240   (320)
    //   mhi   int  80      @ 10,560   (320)
    //   melfT fp32 80*260  @ 10,880   (83,200)
    char* ws = (char*)d_ws;
    float* means = (float*)ws;
    int*   mlo   = (int*)(ws + 10240);
    int*   mhi   = (int*)(ws + 10560);
    float* melfT = (float*)(ws + 10880);

    FbankWrapper_14285061226526_kernel<<<10, 256, 0, stream>>>(means);
    k_setup<<<1, 256, 0, stream>>>(melf, mlo, mhi, melfT);
    k_main<<<2998, 256, 0, stream>>>(wav, window, melfT, mlo, mhi, dcos, dsin, out);
    k_mean<<<dim3(8, BATCH), 256, 0, stream>>>(out, means);
    k_norm<<<dim3((NFRAMES * NMEL + 255) / 256, BATCH), 256, 0, stream>>>(means, out);
}